// Round 8
// baseline (94.673 us; speedup 1.0000x reference)
//
#include <hip/hip_runtime.h>

// LinearAttention fused pipeline, MI355X gfx950. Round 8.
// k_init/k_transpose/k_kv: unchanged from round 7 (verified).
// k_fused2: rebuilt with counted-vmcnt 3-buffer distance-2 pipeline
//   (T3+T4): n-tile 128, BK=32, 8 waves; GEMM1 (Wq.x -> elu1*s*1024 -> Q
//   in swizzled LDS) then GEMM2 (wouth.Q) with wouth prefetched across the
//   publish barrier; fused LayerNorm. Raw s_barrier bracketed by IR memory
//   fences + sched_barrier(0) (round-6 race fix, rule 18/21 discipline).

#define NB 16
#define NC 256
#define NN 4096
#define LN_EPS 1e-5f
#define IOSCALE (1.0f/1024.0f)

typedef _Float16 f16;
typedef _Float16 f16x8 __attribute__((ext_vector_type(8)));
typedef _Float16 f16x4v __attribute__((ext_vector_type(4)));
typedef float f32x4 __attribute__((ext_vector_type(4)));

typedef __attribute__((address_space(1))) const unsigned int* as1cu32;
typedef __attribute__((address_space(3))) unsigned int* as3u32;

__device__ __forceinline__ void gload16(const void* g, void* l) {
  __builtin_amdgcn_global_load_lds((as1cu32)g, (as3u32)l, 16, 0, 0);
}
__device__ __forceinline__ float elu1(float x) {
  return x > 0.f ? x + 1.f : __expf(x);
}
#define MFMA16 __builtin_amdgcn_mfma_f32_16x16x32_f16

#define FENCE() asm volatile("" ::: "memory")
#define SBAR()                                  \
  do {                                          \
    FENCE();                                    \
    __builtin_amdgcn_sched_barrier(0);          \
    __builtin_amdgcn_s_barrier();               \
    __builtin_amdgcn_sched_barrier(0);          \
    FENCE();                                    \
  } while (0)

template <int N> __device__ __forceinline__ void waitv() {
  if constexpr (N == 0) asm volatile("s_waitcnt vmcnt(0)" ::: "memory");
  else if constexpr (N == 2) asm volatile("s_waitcnt vmcnt(2)" ::: "memory");
  else asm volatile("s_waitcnt vmcnt(3)" ::: "memory");
}
__device__ __forceinline__ void waitl0() {
  asm volatile("s_waitcnt lgkmcnt(0)" ::: "memory");
}

__global__ __launch_bounds__(256) void k_init(const float* __restrict__ wqkv,
                                              const float* __restrict__ wout,
                                              f16* __restrict__ wh,
                                              f16* __restrict__ wouth,
                                              float* __restrict__ kvden) {
  int i = blockIdx.x * 256 + threadIdx.x;
  wh[i] = (f16)wqkv[i];
  if (i < 65536) wouth[i] = (f16)wout[i];
  if (i < 8192) kvden[i] = 0.f;
}

// x[b][c][n] f32 -> xh[b][n][c] f16. 64x64 tiles via padded LDS.
__global__ __launch_bounds__(256) void k_transpose(const float* __restrict__ x,
                                                   f16* __restrict__ xh) {
  __shared__ float t[64 * 65];
  const int b = blockIdx.z, c0 = blockIdx.y * 64, n0 = blockIdx.x * 64;
  const int tid = threadIdx.x;
#pragma unroll
  for (int i = 0; i < 4; ++i) {
    int lin = tid + i * 256;
    int r = lin >> 4;
    int cg = lin & 15;
    const float4 v = *reinterpret_cast<const float4*>(
        &x[((size_t)(b * NC + c0 + r)) * NN + n0 + cg * 4]);
    t[r * 65 + cg * 4 + 0] = v.x;
    t[r * 65 + cg * 4 + 1] = v.y;
    t[r * 65 + cg * 4 + 2] = v.z;
    t[r * 65 + cg * 4 + 3] = v.w;
  }
  __syncthreads();
#pragma unroll
  for (int i = 0; i < 4; ++i) {
    int lin = tid + i * 256;
    int nr = lin >> 4;
    int cg = lin & 15;
    f16x4v h;
    h[0] = (f16)t[(cg * 4 + 0) * 65 + nr];
    h[1] = (f16)t[(cg * 4 + 1) * 65 + nr];
    h[2] = (f16)t[(cg * 4 + 2) * 65 + nr];
    h[3] = (f16)t[(cg * 4 + 3) * 65 + nr];
    *reinterpret_cast<f16x4v*>(&xh[((size_t)(b * NN + n0 + nr)) * NC + c0 + cg * 4]) = h;
  }
}

// kv/den. Block: 64n x all 256 ch (k&v). 512 thr = 8 waves = 2 ng x 4 cg.
__global__ __launch_bounds__(512, 4) void k_kv(const f16* __restrict__ xh,
                                               const f16* __restrict__ wh,
                                               float* __restrict__ kv,
                                               float* __restrict__ den) {
  __shared__ __align__(16) f16 Xc[2][64 * 32];
  __shared__ __align__(16) f16 Bt[2][512 * 32];
  const int b = blockIdx.y;
  const int n0 = blockIdx.x * 64;
  const int tid = threadIdx.x;
  const int lane = tid & 63;
  const int wv = tid >> 6;
  const int ng = wv >> 2, cg = wv & 3;
  const int l15 = lane & 15, lg = lane >> 4;
  const int srow = lane >> 2;
  const int scol = (((lane & 3) ^ (srow & 3)) * 8);
  const int xu = ((lg ^ (l15 & 3)) << 3);

  f32x4 kacc[2][4] = {};
  f32x4 vacc[2][4] = {};

#pragma unroll
  for (int i = 0; i < 4; ++i) {
    const int inst = wv * 4 + i;
    gload16(wh + (size_t)(256 + inst * 16 + srow) * NC + scol, &Bt[0][inst * 512]);
  }
  if (wv < 4)
    gload16(xh + ((size_t)(b * NN + n0 + wv * 16 + srow)) * NC + scol, &Xc[0][wv * 512]);
  __syncthreads();

  for (int s = 0; s < 8; ++s) {
    const int cb = s & 1, nb = (s + 1) & 1;
    if (s < 7) {
      const int c0 = (s + 1) * 32;
#pragma unroll
      for (int i = 0; i < 4; ++i) {
        const int inst = wv * 4 + i;
        gload16(wh + (size_t)(256 + inst * 16 + srow) * NC + c0 + scol, &Bt[nb][inst * 512]);
      }
      if (wv < 4)
        gload16(xh + ((size_t)(b * NN + n0 + wv * 16 + srow)) * NC + c0 + scol, &Xc[nb][wv * 512]);
    }
    const f16x8 a0 = *(const f16x8*)(&Xc[cb][(ng * 32 + l15) * 32 + xu]);
    const f16x8 a1 = *(const f16x8*)(&Xc[cb][(ng * 32 + 16 + l15) * 32 + xu]);
#pragma unroll
    for (int f = 0; f < 4; ++f) {
      const f16x8 bk = *(const f16x8*)(&Bt[cb][(cg * 64 + f * 16 + l15) * 32 + xu]);
      kacc[0][f] = MFMA16(a0, bk, kacc[0][f], 0, 0, 0);
      kacc[1][f] = MFMA16(a1, bk, kacc[1][f], 0, 0, 0);
      const f16x8 bv = *(const f16x8*)(&Bt[cb][(256 + cg * 64 + f * 16 + l15) * 32 + xu]);
      vacc[0][f] = MFMA16(a0, bv, vacc[0][f], 0, 0, 0);
      vacc[1][f] = MFMA16(a1, bv, vacc[1][f], 0, 0, 0);
    }
    if (s < 7) __syncthreads();
  }

  float pkv[4] = {0.f, 0.f, 0.f, 0.f}, pden[4] = {0.f, 0.f, 0.f, 0.f};
#pragma unroll
  for (int f = 0; f < 4; ++f)
#pragma unroll
    for (int m = 0; m < 2; ++m)
#pragma unroll
      for (int j = 0; j < 4; ++j) {
        const float kk = elu1(kacc[m][f][j]);
        pkv[f] += kk * vacc[m][f][j];
        pden[f] += kk;
      }
#pragma unroll
  for (int f = 0; f < 4; ++f) {
    pkv[f] += __shfl_xor(pkv[f], 16, 64);
    pkv[f] += __shfl_xor(pkv[f], 32, 64);
    pden[f] += __shfl_xor(pden[f], 16, 64);
    pden[f] += __shfl_xor(pden[f], 32, 64);
  }
  if (lane < 16) {
#pragma unroll
    for (int f = 0; f < 4; ++f) {
      const int c = cg * 64 + f * 16 + lane;
      atomicAdd(&kv[b * NC + c], pkv[f]);
      atomicAdd(&den[b * NC + c], pden[f]);
    }
  }
}

// Fused GEMM1+scale -> Q -> GEMM2 -> LN. 512 thr = 8 waves = 4 cg x 2 ng,
// n-tile 128. 3-buffer distance-2 counted-vmcnt pipeline.
__global__ __launch_bounds__(512, 1) void k_fused2(const f16* __restrict__ xh,
                                                   const f16* __restrict__ wh,
                                                   const f16* __restrict__ wouth,
                                                   const float* __restrict__ kv,
                                                   const float* __restrict__ den,
                                                   const float* __restrict__ gamma,
                                                   const float* __restrict__ beta,
                                                   float* __restrict__ out) {
  __shared__ __align__(16) f16 Wt[3 * 256 * 32];   // 48 KB
  __shared__ __align__(16) f16 Xc[3 * 128 * 32];   // 24 KB (LN scratch overlay)
  __shared__ __align__(16) f16 Q[128 * 256];       // 64 KB, 16B-unit XOR swizzle
  __shared__ float s1024[256];                     // 1 KB
  const int b = blockIdx.y;
  const int n0 = blockIdx.x * 128;
  const int tid = threadIdx.x;
  const int lane = tid & 63;
  const int wv = tid >> 6;
  const int cg = wv >> 1, ng = wv & 1;
  const int l15 = lane & 15, lg = lane >> 4;
  const int srow = lane >> 2;
  const int scol = (((lane & 3) ^ (srow & 3)) * 8);
  const int xu = ((lg ^ (l15 & 3)) << 3);

  if (tid < 256)
    s1024[tid] = kv[b * NC + tid] / fmaxf(den[b * NC + tid], 1e-6f) * 1024.0f;
  waitv<0>();   // drain kv/den loads so vmcnt accounting below is exact

  // uniform 3 loads/wave: 1 Xc (16 rows) + 2 Wt (32 rows)
  auto stageC = [&](int c, int buf) {
    const int c0 = c * 32;
    gload16(xh + ((size_t)(b * NN + n0 + wv * 16 + srow)) * NC + c0 + scol,
            &Xc[buf * 4096 + wv * 512]);
    gload16(wh + (size_t)(wv * 32 + srow) * NC + c0 + scol,
            &Wt[buf * 8192 + wv * 1024]);
    gload16(wh + (size_t)(wv * 32 + 16 + srow) * NC + c0 + scol,
            &Wt[buf * 8192 + wv * 1024 + 512]);
  };
  // uniform 2 loads/wave
  auto stageW = [&](int c, int buf) {
    const int c0 = c * 32;
    gload16(wouth + (size_t)(wv * 32 + srow) * NC + c0 + scol,
            &Wt[buf * 8192 + wv * 1024]);
    gload16(wouth + (size_t)(wv * 32 + 16 + srow) * NC + c0 + scol,
            &Wt[buf * 8192 + wv * 1024 + 512]);
  };

  stageC(0, 0);
  stageC(1, 1);
  waitv<3>();   // chunk0 landed (chunk1's 3 still in flight)
  waitl0();     // s1024 ds_write visible
  SBAR();

  // ---- GEMM1: qT = Wq . x^T, chunk s from buf s%3 ----
  f32x4 acc[4][4] = {};
  for (int s = 0; s < 8; ++s) {
    if (s < 6) stageC(s + 2, (s + 2) % 3);
    else stageW(s - 6, (s + 2) % 3);   // prefetch wouth c0,c1 across publish
    {
      const f16* Wb = &Wt[(s % 3) * 8192];
      const f16* Xb = &Xc[(s % 3) * 4096];
      f16x8 a[4], bx[4];
#pragma unroll
      for (int m = 0; m < 4; ++m)
        a[m] = *(const f16x8*)(Wb + (cg * 64 + m * 16 + l15) * 32 + xu);
#pragma unroll
      for (int f = 0; f < 4; ++f)
        bx[f] = *(const f16x8*)(Xb + (ng * 64 + f * 16 + l15) * 32 + xu);
      __builtin_amdgcn_s_setprio(1);
#pragma unroll
      for (int m = 0; m < 4; ++m)
#pragma unroll
        for (int f = 0; f < 4; ++f)
          acc[m][f] = MFMA16(a[m], bx[f], acc[m][f], 0, 0, 0);
      __builtin_amdgcn_s_setprio(0);
    }
    if (s < 6) waitv<3>();   // next chunk landed; newest 3 stay in flight
    else waitv<2>();         // wouth stage is 2 loads/wave
    SBAR();
  }

  // ---- Q publish: Q[n][c] = elu1(q)*s*1024, swizzled by (n&7) ----
#pragma unroll
  for (int m = 0; m < 4; ++m) {
    const int ch = cg * 64 + m * 16 + lg * 4;
    const float4 sv = *reinterpret_cast<const float4*>(&s1024[ch]);
    const int u = ch >> 3;
#pragma unroll
    for (int f = 0; f < 4; ++f) {
      const int n = ng * 64 + f * 16 + l15;
      f16x4v h;
      h[0] = (f16)(elu1(acc[m][f][0]) * sv.x);
      h[1] = (f16)(elu1(acc[m][f][1]) * sv.y);
      h[2] = (f16)(elu1(acc[m][f][2]) * sv.z);
      h[3] = (f16)(elu1(acc[m][f][3]) * sv.w);
      *reinterpret_cast<f16x4v*>(&Q[n * 256 + ((u ^ (n & 7)) << 3) + (ch & 7)]) = h;
    }
  }
  waitv<2>();   // wouth c0 landed (c1 in flight)
  waitl0();     // Q writes visible
  SBAR();

  // ---- GEMM2: out = wouth . Q, w-chunk s from buf (s+2)%3 ----
  f32x4 acc2[4][4] = {};
  for (int s = 0; s < 8; ++s) {
    if (s < 6) stageW(s + 2, (s + 1) % 3);
    {
      const f16* Wb = &Wt[((s + 2) % 3) * 8192];
      f16x8 a[4], bq[4];
#pragma unroll
      for (int m = 0; m < 4; ++m)
        a[m] = *(const f16x8*)(Wb + (cg * 64 + m * 16 + l15) * 32 + xu);
#pragma unroll
      for (int f = 0; f < 4; ++f) {
        const int n = ng * 64 + f * 16 + l15;
        const int U = s * 4 + lg;
        bq[f] = *(const f16x8*)(&Q[n * 256 + ((U ^ (n & 7)) << 3)]);
      }
      __builtin_amdgcn_s_setprio(1);
#pragma unroll
      for (int m = 0; m < 4; ++m)
#pragma unroll
        for (int f = 0; f < 4; ++f)
          acc2[m][f] = MFMA16(a[m], bq[f], acc2[m][f], 0, 0, 0);
      __builtin_amdgcn_s_setprio(0);
    }
    if (s < 6) { waitv<2>(); SBAR(); }
    else if (s == 6) { waitv<0>(); SBAR(); }
  }

  // ---- LayerNorm over o (256) per column n; scratch overlays Xc ----
  float* red1 = (float*)(&Xc[0]);      // [4][128]
  float* red2 = red1 + 512;
  float* smu = red2 + 512;             // [128]
  float* srs = smu + 128;
  float s1[4] = {0, 0, 0, 0}, s2[4] = {0, 0, 0, 0};
#pragma unroll
  for (int f = 0; f < 4; ++f)
#pragma unroll
    for (int m = 0; m < 4; ++m)
#pragma unroll
      for (int j = 0; j < 4; ++j) {
        const float v = acc2[m][f][j];
        s1[f] += v;
        s2[f] += v * v;
      }
#pragma unroll
  for (int f = 0; f < 4; ++f) {
    s1[f] += __shfl_xor(s1[f], 16, 64);
    s1[f] += __shfl_xor(s1[f], 32, 64);
    s2[f] += __shfl_xor(s2[f], 16, 64);
    s2[f] += __shfl_xor(s2[f], 32, 64);
  }
  __syncthreads();   // all waves past GEMM2 LDS reads before Xc overlay
  if (lane < 16) {
#pragma unroll
    for (int f = 0; f < 4; ++f) {
      const int col = ng * 64 + f * 16 + lane;
      red1[cg * 128 + col] = s1[f];
      red2[cg * 128 + col] = s2[f];
    }
  }
  __syncthreads();
  if (tid < 128) {
    const float a1 = red1[tid] + red1[128 + tid] + red1[256 + tid] + red1[384 + tid];
    const float a2 = red2[tid] + red2[128 + tid] + red2[256 + tid] + red2[384 + tid];
    const float mu = a1 * (IOSCALE / 256.f);
    const float e2 = a2 * (IOSCALE * IOSCALE / 256.f);
    smu[tid] = mu;
    srs[tid] = rsqrtf(e2 - mu * mu + LN_EPS);
  }
  __syncthreads();
#pragma unroll
  for (int m = 0; m < 4; ++m) {
    const int ob = cg * 64 + m * 16 + lg * 4;
#pragma unroll
    for (int j = 0; j < 4; ++j) {
      const int o = ob + j;
      const float g = gamma[o], be = beta[o];
#pragma unroll
      for (int f = 0; f < 4; ++f) {
        const int col = ng * 64 + f * 16 + l15;
        const float v = acc2[m][f][j] * IOSCALE;
        out[((size_t)(b * NC + o)) * NN + n0 + col] = (v - smu[col]) * srs[col] * g + be;
      }
    }
  }
}

extern "C" void kernel_launch(void* const* d_in, const int* in_sizes, int n_in,
                              void* d_out, int out_size, void* d_ws, size_t ws_size,
                              hipStream_t stream) {
  const float* x = (const float*)d_in[0];
  const float* w_qkv = (const float*)d_in[1];
  const float* w_out = (const float*)d_in[2];
  const float* ln_g = (const float*)d_in[3];
  const float* ln_b = (const float*)d_in[4];
  float* out = (float*)d_out;

  char* wsb = (char*)d_ws;
  const size_t OFF_WH = 0;                        // 768*256*2 = 393216
  const size_t OFF_WOUTH = 393216;                // 256*256*2 = 131072
  const size_t OFF_XH = OFF_WOUTH + 131072;       // 32 MiB
  const size_t OFF_KV = OFF_XH + 33554432;        // 16 KiB
  const size_t OFF_DEN = OFF_KV + 16384;          // 16 KiB

  f16* wh = (f16*)(wsb + OFF_WH);
  f16* wouth = (f16*)(wsb + OFF_WOUTH);
  f16* xh = (f16*)(wsb + OFF_XH);
  float* kv = (float*)(wsb + OFF_KV);
  float* den = (float*)(wsb + OFF_DEN);

  k_init<<<768, 256, 0, stream>>>(w_qkv, w_out, wh, wouth, kv);
  k_transpose<<<dim3(64, 4, 16), 256, 0, stream>>>(x, xh);
  k_kv<<<dim3(64, 16), 512, 0, stream>>>(xh, wh, kv, den);
  k_fused2<<<dim3(32, 16), 512, 0, stream>>>(xh, wh, wouth, kv, den, ln_g, ln_b, out);
}